// Round 8
// baseline (325.736 us; speedup 1.0000x reference)
//
#include <hip/hip_runtime.h>
#include <hip/hip_bf16.h>

#define B_ 32
#define S_ 2048
#define D_ 512
#define M_ (B_*S_)   // 65536 rows
#define KS_ 16       // K steps of 32 (512/32)

typedef __bf16 bf16x8 __attribute__((ext_vector_type(8)));
typedef float  f32x4  __attribute__((ext_vector_type(4)));

__device__ __forceinline__ float tanh_fast(float x){
  float e2 = __expf(2.f * x);                    // inf for large x -> rcp=0 -> 1
  return 1.f - 2.f * __builtin_amdgcn_rcpf(e2 + 1.f);
}
__device__ __forceinline__ bf16x8 cvt8(f32x4 a, f32x4 b){
  bf16x8 t;
  t[0]=(__bf16)a[0]; t[1]=(__bf16)a[1]; t[2]=(__bf16)a[2]; t[3]=(__bf16)a[3];
  t[4]=(__bf16)b[0]; t[5]=(__bf16)b[1]; t[6]=(__bf16)b[2]; t[7]=(__bf16)b[3];
  return t;
}
__device__ __forceinline__ void gl_lds16(const void* g, void* l){
  __builtin_amdgcn_global_load_lds(
      (const __attribute__((address_space(1))) unsigned int*)g,
      (__attribute__((address_space(3))) unsigned int*)l, 16, 0, 0);
}

// ---- prelude: blocks [0,128) reorder w_v into wvr2[ks][nh][ntl][lane][8];
//      blocks [128,256) qproj[b,d] = q[b]@wq[:,d] + bias[d].
__global__ void k_prep(const float* __restrict__ wv, unsigned short* __restrict__ wvr2,
                       const float* __restrict__ q, const float* __restrict__ wq,
                       const float* __restrict__ bias, float* __restrict__ qp){
  __shared__ float qs[D_];
  __shared__ float red[2][128];
  const int bi = blockIdx.x, t = threadIdx.x;
  if (bi < 128){
    int g = bi*256 + t;              // 0..32767 = 512 frags x 64 lanes
    int lane = g & 63, frag = g >> 6;
    int ntl = frag & 7, nh = (frag>>3)&3, ks = frag>>5;
    int nt = nh*8 + ntl;
    int k0 = ks*32 + (lane>>4)*8;    // quad*8
    int d  = nt*16 + (lane&15);
    bf16x8 v;
    #pragma unroll
    for (int j=0;j<8;++j) v[j] = (__bf16)wv[(size_t)(k0+j)*D_ + d];
    *reinterpret_cast<uint4*>(wvr2 + ((size_t)frag*64 + lane)*8) =
        __builtin_bit_cast(uint4, v);
  } else {
    int j  = bi - 128;               // 0..127
    int b  = j >> 2, dg = j & 3;
    int dl = t & 127, eg = t >> 7;   // 2-way k-split
    int d  = dg*128 + dl;
    for (int e=t; e<D_; e+=256) qs[e] = q[b*D_+e];
    __syncthreads();
    float acc = 0.f;
    #pragma unroll 8
    for (int i=0;i<256;++i){
      int e = eg*256 + i;
      acc = fmaf(qs[e], wq[(size_t)e*D_+d], acc);
    }
    red[eg][dl] = acc;
    __syncthreads();
    if (eg == 0)
      qp[b*D_+d] = red[0][dl] + red[1][dl] + bias[d];
  }
}

// ---- m97-form GEMM + epilogue, A staged as FP32 via DMA (no value copy) ----
// 2048 blocks = 512 row-tiles(128) x 4 col-slabs(128). 4 waves: wh=row half,
// wc=col half; per wave 4mt x 4nt of 16x16x32 bf16 MFMA.
// A LDS: 128 rows x 8 slots of 16B fp32, slot = chunk ^ (row&7) XOR swizzle
// (applied on DMA source addr; dst stays base+lane*16). B: bf16 frag slabs.
__launch_bounds__(256)
__global__ void k_energy(const float* __restrict__ value,
                         const unsigned short* __restrict__ wvr2,
                         const float* __restrict__ qp,
                         const float* __restrict__ energy,
                         const float* __restrict__ conv_w,
                         const float* __restrict__ conv_b,
                         const float* __restrict__ score_w,
                         float* __restrict__ sp){
  __shared__ __align__(16) float          As[2][4096];   // 16 KB per buf
  __shared__ __align__(16) unsigned short Bs[2][4096];   //  8 KB per buf
  __shared__ float red[2][128];

  const int t    = threadIdx.x;
  const int wave = t >> 6;
  const int lane = t & 63;
  const int quad = lane >> 4;
  const int lm   = lane & 15;
  const int wh   = wave & 1;
  const int wc   = wave >> 1;
  const int rt   = blockIdx.x >> 2;
  const int nh   = blockIdx.x & 3;
  const int row0 = rt * 128;
  const int b    = row0 >> 11;       // 128 | 2048
  const int s0   = row0 & (S_-1);

  // A DMA sources: unit u = i*256+t -> row=u>>3, slot=u&7, chunk=slot^(row&7)
  const float* gA[4];
  #pragma unroll
  for (int i=0;i<4;++i){
    int u   = i*256 + t;
    int row = u >> 3;
    int dc  = (u & 7) ^ (row & 7);
    gA[i] = value + (size_t)(row0 + row)*D_ + dc*4;
  }
  // B DMA source: per step (ks*4+nh)*4096 elems; 2 units/thread
  const unsigned short* gB = wvr2 + (size_t)nh*4096 + t*8;

  f32x4 acc[4][4];
  #pragma unroll
  for (int mt=0;mt<4;++mt)
    #pragma unroll
    for (int nt=0;nt<4;++nt)
      acc[mt][nt] = (f32x4){0.f,0.f,0.f,0.f};

  // prologue: stage ks=0 into buf 0
  #pragma unroll
  for (int i=0;i<4;++i) gl_lds16(gA[i], &As[0][(i*256 + t)*4]);
  gl_lds16(gB,        &Bs[0][t*8]);
  gl_lds16(gB + 2048, &Bs[0][2048 + t*8]);
  __syncthreads();

  for (int ks=0; ks<KS_; ++ks){
    const int buf = ks & 1;
    if (ks < KS_-1){
      #pragma unroll
      for (int i=0;i<4;++i) gl_lds16(gA[i] + (ks+1)*32, &As[buf^1][(i*256 + t)*4]);
      gl_lds16(gB + (ks+1)*16384,        &Bs[buf^1][t*8]);
      gl_lds16(gB + (ks+1)*16384 + 2048, &Bs[buf^1][2048 + t*8]);
    }
    const float* Ab = &As[buf][0];
    const unsigned short* Bb = &Bs[buf][0];
    bf16x8 a[4], bf[4];
    #pragma unroll
    for (int mt=0;mt<4;++mt){
      int arow  = wh*64 + mt*16 + lm;
      int slot0 = (quad*2)     ^ (lm & 7);
      int slot1 = (quad*2 + 1) ^ (lm & 7);
      f32x4 p0 = *reinterpret_cast<const f32x4*>(&Ab[arow*32 + slot0*4]);
      f32x4 p1 = *reinterpret_cast<const f32x4*>(&Ab[arow*32 + slot1*4]);
      a[mt] = cvt8(p0, p1);
    }
    #pragma unroll
    for (int nt=0;nt<4;++nt)
      bf[nt] = *reinterpret_cast<const bf16x8*>(&Bb[((wc*4+nt)*64 + lane)*8]);
    #pragma unroll
    for (int mt=0;mt<4;++mt)
      #pragma unroll
      for (int nt=0;nt<4;++nt)
        acc[mt][nt] = __builtin_amdgcn_mfma_f32_16x16x32_bf16(a[mt], bf[nt], acc[mt][nt], 0,0,0);
    __syncthreads();
  }

  // epilogue: per-lane d = nh*128 + wc*64 + nt*16 + lm
  float sw[4], c0[4], c1[4], c2[4], cb[4], qv[4];
  #pragma unroll
  for (int nt=0; nt<4; ++nt){
    int d = nh*128 + wc*64 + nt*16 + lm;
    sw[nt] = score_w[d];
    c0[nt] = conv_w[d*3+0];
    c1[nt] = conv_w[d*3+1];
    c2[nt] = conv_w[d*3+2];
    cb[nt] = conv_b[d];
    qv[nt] = qp[b*D_+d];
  }
  const float* eB = energy + b*S_;
  #pragma unroll
  for (int mt=0; mt<4; ++mt){
    #pragma unroll
    for (int r=0;r<4;++r){
      int sl = wh*64 + mt*16 + quad*4 + r;      // C/D layout: row=quad*4+reg
      int s  = s0 + sl;
      float em1 = (s > 0)    ? eB[s-1] : 0.f;
      float e0  =              eB[s];
      float ep1 = (s < S_-1) ? eB[s+1] : 0.f;
      float p = 0.f;
      #pragma unroll
      for (int nt=0; nt<4; ++nt){
        float h = acc[mt][nt][r] + qv[nt]
                + fmaf(c0[nt],em1, fmaf(c1[nt],e0, fmaf(c2[nt],ep1, cb[nt])));
        p = fmaf(sw[nt], tanh_fast(h), p);
      }
      #pragma unroll
      for (int m=1; m<16; m<<=1) p += __shfl_xor(p, m, 64);   // reduce 16 cols
      if (lm == 0) red[wc][sl] = p;
    }
  }
  __syncthreads();
  if (t < 128)
    sp[(size_t)nh*M_ + row0 + t] = red[0][t] + red[1][t];
}

// ---- softmax over S per batch (sums 4 col-slab partials); score_b cancels ----
__global__ void k_softmax(const float* __restrict__ sp,
                          float* __restrict__ out_align){
  int b = blockIdx.x, t = threadIdx.x;
  int lane = t & 63, wid = t >> 6;
  float v[8], mx = -3.4e38f;
  #pragma unroll
  for (int i=0;i<8;++i){
    int s = t + i*256;
    float sc = sp[0*M_+b*S_+s] + sp[1*M_+b*S_+s] + sp[2*M_+b*S_+s] + sp[3*M_+b*S_+s];
    v[i] = sc;
    mx = fmaxf(mx, sc);
  }
  __shared__ float red[4], red2[4];
  #pragma unroll
  for (int m=1;m<64;m<<=1) mx = fmaxf(mx, __shfl_xor(mx, m, 64));
  if (lane==0) red[wid] = mx;
  __syncthreads();
  mx = fmaxf(fmaxf(red[0],red[1]), fmaxf(red[2],red[3]));
  float sum = 0.f;
  #pragma unroll
  for (int i=0;i<8;++i){ v[i] = __expf(v[i]-mx); sum += v[i]; }
  #pragma unroll
  for (int m=1;m<64;m<<=1) sum += __shfl_xor(sum, m, 64);
  if (lane==0) red2[wid] = sum;
  __syncthreads();
  sum = red2[0]+red2[1]+red2[2]+red2[3];
  float inv = 1.f/sum;
  #pragma unroll
  for (int i=0;i<8;++i) out_align[b*S_ + t + i*256] = v[i]*inv;
}

// ---- context partials: block (sc,b) covers 128 s rows; fp32 value ----
__launch_bounds__(512)
__global__ void k_ctx(const float* __restrict__ value,
                      const float* __restrict__ align,
                      float* __restrict__ cpart){
  int b = blockIdx.y, sc = blockIdx.x;   // sc: 0..15
  int t = threadIdx.x;                   // 512
  int r = t >> 7;            // 0..3 (s subgroup)
  int c = (t & 127) * 4;     // 16B per thread
  __shared__ float als[128];
  __shared__ float lred[4][D_];
  if (t < 128) als[t] = align[b*S_ + sc*128 + t];
  __syncthreads();
  f32x4 acc = (f32x4){0.f,0.f,0.f,0.f};
  #pragma unroll 8
  for (int i=0;i<32;++i){
    int sl = i*4 + r;
    float al = als[sl];
    f32x4 vv = *reinterpret_cast<const f32x4*>(
                 value + ((size_t)(b*S_ + sc*128 + sl))*D_ + c);
    acc += al * vv;
  }
  #pragma unroll
  for (int j=0;j<4;++j) lred[r][c+j] = acc[j];
  __syncthreads();
  if (r == 0){
    #pragma unroll
    for (int j=0;j<4;++j)
      cpart[((size_t)(b*16+sc))*D_ + c + j] =
          lred[0][c+j] + lred[1][c+j] + lred[2][c+j] + lred[3][c+j];
  }
}

__global__ void k_ctx_reduce(const float* __restrict__ cpart,
                             float* __restrict__ out_ctx){
  int idx = blockIdx.x*256 + threadIdx.x;   // 0..16383
  int b = idx >> 9, d = idx & 511;
  float s = 0.f;
  #pragma unroll
  for (int j=0;j<16;++j) s += cpart[((size_t)(b*16+j))*D_ + d];
  out_ctx[idx] = s;
}

extern "C" void kernel_launch(void* const* d_in, const int* in_sizes, int n_in,
                              void* d_out, int out_size, void* d_ws, size_t ws_size,
                              hipStream_t stream){
  const float* query   = (const float*)d_in[0];
  const float* value   = (const float*)d_in[1];
  const float* energy  = (const float*)d_in[2];
  const float* conv_w  = (const float*)d_in[3];
  const float* conv_b  = (const float*)d_in[4];
  const float* w_q     = (const float*)d_in[5];
  const float* w_v     = (const float*)d_in[6];
  const float* bias    = (const float*)d_in[7];
  const float* score_w = (const float*)d_in[8];
  // score_b (d_in[9]) cancels in softmax -> unused.

  char* ws = (char*)d_ws;
  unsigned short* wvr2 = (unsigned short*)(ws);           // 512 KB (bf16 frags)
  float* qp    = (float*)(ws + (512<<10));                // 64 KB
  float* sp    = (float*)(ws + (576<<10));                // 1 MB (4 x 65536 f32)
  float* cpart = (float*)(ws + (1600<<10));               // 1 MB (32*16 x 512 f32)
  // total ~2.6 MB

  float* out_ctx   = (float*)d_out;                       // [B, D] fp32
  float* out_align = out_ctx + B_*D_;                     // [B, S] fp32

  k_prep      <<<dim3(256),       dim3(256), 0, stream>>>(w_v, wvr2, query, w_q, bias, qp);
  k_energy    <<<dim3(2048),      dim3(256), 0, stream>>>(value, wvr2, qp, energy,
                                                          conv_w, conv_b, score_w, sp);
  k_softmax   <<<dim3(B_),        dim3(256), 0, stream>>>(sp, out_align);
  k_ctx       <<<dim3(16,B_),     dim3(512), 0, stream>>>(value, out_align, cpart);
  k_ctx_reduce<<<dim3(B_*D_/256), dim3(256), 0, stream>>>(cpart, out_ctx);
}